// Round 6
// baseline (331.852 us; speedup 1.0000x reference)
//
#include <hip/hip_runtime.h>
#include <hip/hip_bf16.h>

// AngularMarginLoss: B=2048, D=256, C=100000
// loss = -mean_b( num_b - log(exp(num_b) + sum_{c!=t_b} exp(30*cos_bc) + 1e-6) )
// num_b = 30*cos(acos(clip(cos_bt)) + 0.2)
//
// Round-13b (compile fix: nt builtins need clang ext_vector types, not
// HIP_vector_type float4). Theory unchanged from R13:
// The wall all rounds shared was never LDS or MFMA: every block re-reads the
// full 1MB embF -> 1.6GB of B-traffic, and the once-only W stream (100MB)
// continuously evicts embF from each XCD's 4MB L2, so B came from L3/fabric
// at ~9-12 TB/s = 130-180us (fits R8=152, R10=132, R12=184). Fixes:
//  * W prologue loads + partial stores are NON-TEMPORAL (nt): W stops
//    polluting L2 -> embF (1MB/XCD, re-touched constantly) stays L2-resident
//    -> B-stream at L2 rate ~34.5 TB/s ~= 46us, overlapped with MFMA (42us)
//    and LDS (~30us).
//  * Full-tile B ping-pong restored (R12 dropped it): L2 latency hides under
//    the 32-MFMA tile. __launch_bounds__(512) (no min-blocks) so the
//    allocator has room (~190 regs); R11's spill disaster came from capping.
//  * Keep: 32x32x16 MFMA (half LDS traffic of 16x16), conflict-free
//    lane-contiguous prologue, embF pre-scaled by 30*log2(e) (exp = 1 exp2).

static constexpr int Bn = 2048;
static constexpr int Dn = 256;
static constexpr int Cn = 100000;
static constexpr int NSLICE = 1564;                 // 64-col slices
static constexpr int CPAD   = NSLICE * 64;          // 100096
static constexpr float OOB_COLS = (float)(CPAD - Cn);   // 96 (exp2(0)=1 each)
static constexpr int NT  = Bn / 32;                 // 64 sample tiles (32-wide)
static constexpr int NWV = 8;                       // waves per block
static constexpr int NTW = NT / NWV;                // 8 tiles per wave

#define SCALE_F 30.0f
#define MARGIN_F 0.2f
#define EPS_F 1e-6f
#define L2E_SCALE 43.2808512266689f   /* 30 * log2(e): exp(30*c) = 2^(L2E*c) */

typedef __attribute__((ext_vector_type(8))) short bf16x8;    // 8 bf16 = 4 VGPRs
typedef __attribute__((ext_vector_type(16))) float f32x16;   // 32x32 acc half
typedef __attribute__((ext_vector_type(4))) float f32x4v;    // nt-load friendly

__device__ __forceinline__ short f2bf_rne(float x) {
    union { float f; unsigned int u; } v; v.f = x;
    unsigned int r = v.u + 0x7fffu + ((v.u >> 16) & 1u);
    return (short)(r >> 16);
}

// ---- kernel 1: fused prep ----
// blocks [0,256)    : pack emb fp32 -> embF (bf16, 32x32x16 MFMA B-fragment
//                     order), PRE-SCALED by 30*log2(e).
//   chunk (t,ks,lane): embF[((t*16+ks)*64+lane)*8 .. +7] = bf16 of
//   L2E * emb[t*32 + (lane&31)][ks*16 + (lane>>5)*8 + j], j=0..7
// blocks [256,768)  : per-sample target cosine -> numv, etv (exact fp32 path)
__global__ __launch_bounds__(256) void k_prep(const float* __restrict__ W,
                                              const float* __restrict__ emb,
                                              const int* __restrict__ tgt,
                                              short* __restrict__ embF,
                                              float* __restrict__ numv,
                                              float* __restrict__ etv) {
    const int blk = blockIdx.x;
    if (blk < 256) {
        const int t     = blk >> 2;                        // sample tile 0..63
        const int chunk = (blk & 3) * 256 + threadIdx.x;   // [0,1024)
        const int ks    = chunk >> 6;                      // 0..15
        const int lane  = chunk & 63;
        const float* src = emb + (size_t)(t * 32 + (lane & 31)) * Dn
                               + ks * 16 + (lane >> 5) * 8;
        float4 x0 = *(const float4*)(src);
        float4 x1 = *(const float4*)(src + 4);
        bf16x8 o;
        o[0] = f2bf_rne(x0.x * L2E_SCALE); o[1] = f2bf_rne(x0.y * L2E_SCALE);
        o[2] = f2bf_rne(x0.z * L2E_SCALE); o[3] = f2bf_rne(x0.w * L2E_SCALE);
        o[4] = f2bf_rne(x1.x * L2E_SCALE); o[5] = f2bf_rne(x1.y * L2E_SCALE);
        o[6] = f2bf_rne(x1.z * L2E_SCALE); o[7] = f2bf_rne(x1.w * L2E_SCALE);
        *(bf16x8*)(embF + (size_t)((t * 16 + ks) * 64 + lane) * 8) = o;
    } else {
        const int b    = (blk - 256) * 4 + (threadIdx.x >> 6);
        const int lane = threadIdx.x & 63;
        const int t    = tgt[b];
        float4 x = *(const float4*)(W + (size_t)t * Dn + lane * 4);
        float4 e = *(const float4*)(emb + b * Dn + lane * 4);
        float dot = x.x * e.x + x.y * e.y + x.z * e.z + x.w * e.w;
        float ss  = x.x * x.x + x.y * x.y + x.z * x.z + x.w * x.w;
#pragma unroll
        for (int o = 1; o < 64; o <<= 1) {
            dot += __shfl_xor(dot, o);
            ss  += __shfl_xor(ss, o);
        }
        if (lane == 0) {
            float cosv = dot / fmaxf(sqrtf(ss), 1e-12f);
            cosv = fminf(fmaxf(cosv, -1.f), 1.f);
            const float num = SCALE_F * cosf(acosf(cosv) + MARGIN_F);
            numv[b] = num;
            etv[b]  = __expf(SCALE_F * cosv);
        }
    }
}

// ---- kernel 2: main fused GEMM + exp row-sum ----
// Block = one 64-class slice, 8 waves (512 thr). Cooperative one-pass
// W-normalize (nt loads) into 32KB LDS (A-frags for 32x32x16), then each
// wave owns 8 sample-tiles of 32, barrier-free, B ping-pong from L2.
__global__ __launch_bounds__(512) void k_main(const float* __restrict__ W,
                                              const short* __restrict__ embF,
                                              float* __restrict__ partial) {
    __shared__ short afrag_sh[2 * 16 * 64 * 8];   // 32 KB: [(ct*16+ks)*64+l]*8
    __shared__ float ssq_sh[8 * 64];              // 2 KB cross-wave norm
    const int tid  = threadIdx.x;
    const int lane = tid & 63;
    const int wv   = tid >> 6;    // wave id 0..7
    const int sl   = blockIdx.x;
    const int cbase = sl * 64;

    // ---- prologue: wave wv handles k-chunk [wv*32, +32) of ALL 64 rows;
    // lane = row. NT loads: W is touched once -> don't evict embF from L2.
    {
        const int c = cbase + lane;
        float v[32];
        if (c < Cn) {
            const f32x4v* wr = (const f32x4v*)(W + (size_t)c * Dn + wv * 32);
#pragma unroll
            for (int j = 0; j < 8; ++j) {
                f32x4v x = __builtin_nontemporal_load(wr + j);
                v[j * 4 + 0] = x.x; v[j * 4 + 1] = x.y;
                v[j * 4 + 2] = x.z; v[j * 4 + 3] = x.w;
            }
        } else {
#pragma unroll
            for (int j = 0; j < 32; ++j) v[j] = 0.0f;
        }
        float ss = 0.0f;
#pragma unroll
        for (int j = 0; j < 32; ++j) ss += v[j] * v[j];
        ssq_sh[wv * 64 + lane] = ss;
        __syncthreads();
        float tot = 0.0f;
#pragma unroll
        for (int w = 0; w < 8; ++w) tot += ssq_sh[w * 64 + lane];
        const float rn = 1.0f / fmaxf(sqrtf(tot), 1e-12f);
        // A layout (32x32x16): frag (ct,ks), lane l': row=ct*32+(l'&31),
        // k = ks*16 + (l'>>5)*8 + j. Here row=lane, k=wv*32+q2*8+j ->
        // ks = 2*wv + (q2>>1), h = q2&1, l' = h*32 + (lane&31).
        const int ct  = lane >> 5;
        const int r31 = lane & 31;
#pragma unroll
        for (int q2 = 0; q2 < 4; ++q2) {
            const int ks = 2 * wv + (q2 >> 1);
            const int h  = q2 & 1;
            bf16x8 a;
#pragma unroll
            for (int j = 0; j < 8; ++j) a[j] = f2bf_rne(v[q2 * 8 + j] * rn);
            *(bf16x8*)(afrag_sh + (size_t)((ct * 16 + ks) * 64 + h * 32 + r31) * 8) = a;
        }
    }
    __syncthreads();

    float* pout = partial + (size_t)sl * Bn;
    const bf16x8* bsrc = (const bf16x8*)embF;   // chunk-indexed (16B units)
    const int t0 = wv * NTW;                    // this wave's 8 sample tiles

    // B fragments for tile t: chunks t*1024 + ks*64 + lane (coalesced 1KB/inst)
    auto load_b = [&](bf16x8* bf, int t) {
        const bf16x8* p = bsrc + ((size_t)t << 10) + lane;
#pragma unroll
        for (int ks = 0; ks < 16; ++ks) bf[ks] = p[ks * 64];
    };

    auto compute = [&](const bf16x8* bf, int t) {
        f32x16 a0 = {0.f,0.f,0.f,0.f,0.f,0.f,0.f,0.f,0.f,0.f,0.f,0.f,0.f,0.f,0.f,0.f};
        f32x16 a1 = {0.f,0.f,0.f,0.f,0.f,0.f,0.f,0.f,0.f,0.f,0.f,0.f,0.f,0.f,0.f,0.f};
#pragma unroll
        for (int ks = 0; ks < 16; ++ks) {
            const short* ap = afrag_sh + (size_t)(ks * 64 + lane) * 8;
            bf16x8 w0 = *(const bf16x8*)(ap);               // ct=0
            bf16x8 w1 = *(const bf16x8*)(ap + 16 * 64 * 8); // ct=1
            a0 = __builtin_amdgcn_mfma_f32_32x32x16_bf16(w0, bf[ks], a0, 0, 0, 0);
            a1 = __builtin_amdgcn_mfma_f32_32x32x16_bf16(w1, bf[ks], a1, 0, 0, 0);
        }
        // D layout (32x32): col=lane&31=sample; 16 regs x 2 lane-halves cover
        // each class-row once. d = 30*log2e*cos -> exp2 directly.
        float s0 = 0.f, s1 = 0.f, s2 = 0.f, s3 = 0.f;
#pragma unroll
        for (int r = 0; r < 16; r += 4) {
            s0 += __builtin_amdgcn_exp2f(a0[r + 0]);
            s1 += __builtin_amdgcn_exp2f(a0[r + 1]);
            s2 += __builtin_amdgcn_exp2f(a0[r + 2]);
            s3 += __builtin_amdgcn_exp2f(a0[r + 3]);
            s0 += __builtin_amdgcn_exp2f(a1[r + 0]);
            s1 += __builtin_amdgcn_exp2f(a1[r + 1]);
            s2 += __builtin_amdgcn_exp2f(a1[r + 2]);
            s3 += __builtin_amdgcn_exp2f(a1[r + 3]);
        }
        float s = (s0 + s1) + (s2 + s3);
        s += __shfl_xor(s, 32);                     // merge row-halves
        if (lane < 32)
            __builtin_nontemporal_store(s, pout + t * 32 + lane);  // 128B, nt
    };

    bf16x8 b0[16], b1[16];
    load_b(b0, t0);
    for (int i = 0; i < NTW; i += 2) {
        load_b(b1, t0 + i + 1);                          // prefetch next tile
        compute(b0, t0 + i);
        load_b(b0, (i + 2) < NTW ? (t0 + i + 2) : t0);   // overrun-clamped
        compute(b1, t0 + i + 1);
    }
}

// ---- kernel 3: fused rowsum + loss ----
// 128 blocks x 256 thr; block owns 16 samples; tid = chunk*16 + l.
__global__ __launch_bounds__(256) void k_finish(const float* __restrict__ partial,
                                                const float* __restrict__ numv,
                                                const float* __restrict__ etv,
                                                float* __restrict__ out) {
    __shared__ float red[16];
    const int l     = threadIdx.x & 15;          // sample within block
    const int chunk = threadIdx.x >> 4;          // 0..15
    const int b  = blockIdx.x * 16 + l;

    if (threadIdx.x < 16) red[threadIdx.x] = 0.0f;
    __syncthreads();

    float acc = 0.0f;
    for (int s = chunk; s < NSLICE; s += 16) acc += partial[(size_t)s * Bn + b];
    // wave holds 4 chunks x 16 samples: fold chunks in-wave first
    acc += __shfl_xor(acc, 16);
    acc += __shfl_xor(acc, 32);
    if ((threadIdx.x & 63) < 16) atomicAdd(&red[l], acc);
    __syncthreads();

    if (threadIdx.x < 16) {
        const int bb = blockIdx.x * 16 + threadIdx.x;
        const float num  = numv[bb];
        const float excl = red[threadIdx.x] - OOB_COLS - etv[bb];  // drop pad + target
        float term = num - logf(__expf(num) + excl + EPS_F);
#pragma unroll
        for (int o = 1; o < 16; o <<= 1) term += __shfl_xor(term, o);
        if (threadIdx.x == 0) atomicAdd(out, -term / (float)Bn);
    }
}

extern "C" void kernel_launch(void* const* d_in, const int* in_sizes, int n_in,
                              void* d_out, int out_size, void* d_ws, size_t ws_size,
                              hipStream_t stream) {
    const float* emb = (const float*)d_in[0];   // 2048*256
    const float* W   = (const float*)d_in[1];   // 100000*256
    const int*   tgt = (const int*)d_in[2];     // 2048
    float* out = (float*)d_out;

    char* ws = (char*)d_ws;
    short* embF    = (short*)ws;                             // 1 MB (fragment order)
    float* partial = (float*)(ws + (1 << 20));               // 1564*2048*4 = 12.8 MB
    float* numv    = partial + (size_t)NSLICE * Bn;          // 8 KB
    float* etv     = numv + Bn;                              // 8 KB

    hipMemsetAsync(out, 0, sizeof(float), stream);
    k_prep<<<768, 256, 0, stream>>>(W, emb, tgt, embF, numv, etv);
    k_main<<<NSLICE, 512, 0, stream>>>(W, embF, partial);
    k_finish<<<128, 256, 0, stream>>>(partial, numv, etv, out);
}